// Round 5
// baseline (23.160 us; speedup 1.0000x reference)
//
#include <hip/hip_runtime.h>
#include <hip/hip_bf16.h>

#define NB 2
#define NQS 1024
#define NKS 1024
#define DD 512
#define HH 32
#define NKROW (NB * NKS)  // 2048 key rows; query rows follow in E
#define W1S 34            // LDS stride: conflict-free B-frag reads

typedef __attribute__((ext_vector_type(8))) short bf16x8;
typedef __attribute__((ext_vector_type(4))) float f32x4;

static __device__ __forceinline__ float fexp2(float x) {
#if __has_builtin(__builtin_amdgcn_exp2f)
  return __builtin_amdgcn_exp2f(x);
#else
  float r; asm("v_exp_f32 %0, %1" : "=v"(r) : "v"(x)); return r;
#endif
}
static __device__ __forceinline__ float frcp(float x) {
#if __has_builtin(__builtin_amdgcn_rcpf)
  return __builtin_amdgcn_rcpf(x);
#else
  float r; asm("v_rcp_f32 %0, %1" : "=v"(r) : "v"(x)); return r;
#endif
}

// Phase 1 (MFMA, split-K x4): E[row][h] = exp2(S*(row.W1col + (isq? b1 : 0))).
// 256 blocks x 256 thr. Block = 16 rows; wave w owns K-range [w*128, w*128+128).
// W1 half staged to LDS bf16 stride-34; split-K reduce via LDS; exp2 epilogue.
__global__ __launch_bounds__(256) void p1_proj_mfma(
    const float* __restrict__ keys, const float* __restrict__ queries,
    const float* __restrict__ W1, const float* __restrict__ b1,
    float* __restrict__ E) {
  __shared__ __hip_bfloat16 W1L[DD * W1S];
  __shared__ float red[4 * 2 * 64 * 4];  // [wave][ntile][lane][reg]
  const float S = 2.8853900817779268f;   // 2*log2(e)
  const int tid = threadIdx.x;
  const int row0 = blockIdx.x * 16;
  const bool isq = row0 >= NKROW;
  const float* src = isq ? queries + (size_t)(row0 - NKROW) * DD
                         : keys + (size_t)row0 * DD;
  const float* w1 = W1 + (isq ? (size_t)DD * HH : 0);
#pragma unroll
  for (int s = 0; s < 16; ++s) {
    const int f = tid + s * 256;
    float4 v = *(const float4*)(w1 + (size_t)f * 4);
    const int k = f >> 3, h0 = (f & 7) * 4;
    __hip_bfloat16* p = &W1L[k * W1S + h0];
    p[0] = __float2bfloat16(v.x); p[1] = __float2bfloat16(v.y);
    p[2] = __float2bfloat16(v.z); p[3] = __float2bfloat16(v.w);
  }
  __syncthreads();
  const int l = tid & 63, w = tid >> 6;
  const int m = l & 15, kq = l >> 4;
  f32x4 acc0 = {0.f, 0.f, 0.f, 0.f}, acc1 = {0.f, 0.f, 0.f, 0.f};
  const float* arow = src + (size_t)m * DD + w * 128 + kq * 8;
  union Frag { bf16x8 v; __hip_bfloat16 e[8]; };
#pragma unroll
  for (int s = 0; s < 4; ++s) {
    const int kb = w * 128 + s * 32;
    float4 a0 = *(const float4*)(arow + s * 32);
    float4 a1 = *(const float4*)(arow + s * 32 + 4);
    Frag af, bf0, bf1;
    af.e[0] = __float2bfloat16(a0.x); af.e[1] = __float2bfloat16(a0.y);
    af.e[2] = __float2bfloat16(a0.z); af.e[3] = __float2bfloat16(a0.w);
    af.e[4] = __float2bfloat16(a1.x); af.e[5] = __float2bfloat16(a1.y);
    af.e[6] = __float2bfloat16(a1.z); af.e[7] = __float2bfloat16(a1.w);
    const __hip_bfloat16* bp = &W1L[(kb + kq * 8) * W1S + m];
#pragma unroll
    for (int j = 0; j < 8; ++j) {
      bf0.e[j] = bp[j * W1S];
      bf1.e[j] = bp[j * W1S + 16];
    }
    acc0 = __builtin_amdgcn_mfma_f32_16x16x32_bf16(af.v, bf0.v, acc0, 0, 0, 0);
    acc1 = __builtin_amdgcn_mfma_f32_16x16x32_bf16(af.v, bf1.v, acc1, 0, 0, 0);
  }
  *(f32x4*)(&red[((w * 2 + 0) * 64 + l) * 4]) = acc0;
  *(f32x4*)(&red[((w * 2 + 1) * 64 + l) * 4]) = acc1;
  __syncthreads();
#pragma unroll
  for (int u = 0; u < 2; ++u) {
    const int o = tid + u * 256;
    const int rr = o >> 5, h = o & 31;
    const int t = h >> 4, mm = h & 15;
    const int ll = ((rr >> 2) << 4) | mm, r = rr & 3;
    float sum = red[(0 + t) * 256 + ll * 4 + r] + red[(2 + t) * 256 + ll * 4 + r] +
                red[(4 + t) * 256 + ll * 4 + r] + red[(6 + t) * 256 + ll * 4 + r];
    if (isq) sum += b1[h];
    E[(size_t)(row0 + rr) * HH + h] = fexp2(S * sum);
  }
}

// Phase 2, 8-term rcp merge: for each group of 4 h-pairs, combine the pair
// rationals (n_p, d_p) in a 2-level tree so ONE rcp serves 8 h-terms:
//   pair: d_p = (1+ek0*eq0)(1+ek1*eq1);  n_p = C01 + Aa*eq1 + Bb*eq0
//   n01 = n0*d1 + n1*d0, d01 = d0*d1;  n = n01*d23 + n23*d01, d = d01*d23
//   acc += n * rcp(d)
// 30 VALU + 1 trans per 8 terms (vs 24 V + 2 T): trans 16->4 per element.
__global__ __launch_bounds__(256) void p2_score(
    const float* __restrict__ E, const float* __restrict__ W2,
    const float* __restrict__ b2, float* __restrict__ out) {
  const int tid = threadIdx.x;
  const int kl = tid & 63;
  const int qg = __builtin_amdgcn_readfirstlane(tid >> 6);  // wave-uniform
  const int k0 = blockIdx.x * 64, q0 = blockIdx.y * 32, b = blockIdx.z;
  const float* ekp = E + (size_t)(b * NKS + k0 + kl) * HH;
  float ek[HH];
#pragma unroll
  for (int i = 0; i < 8; ++i) {
    float4 v = *(const float4*)(ekp + i * 4);
    ek[i * 4 + 0] = v.x; ek[i * 4 + 1] = v.y;
    ek[i * 4 + 2] = v.z; ek[i * 4 + 3] = v.w;
  }
  float c0 = b2[0];
  float w2v[HH];
#pragma unroll
  for (int h = 0; h < HH; ++h) { float ww = W2[h]; c0 += ww; w2v[h] = -2.f * ww; }
  float Aa[16], Bb[16], C01[16];
#pragma unroll
  for (int i = 0; i < 16; ++i) {
    Aa[i] = w2v[2 * i] * ek[2 * i + 1];
    Bb[i] = w2v[2 * i + 1] * ek[2 * i];
    C01[i] = w2v[2 * i] + w2v[2 * i + 1];
  }
  const float* eqb = E + ((size_t)NKROW + (size_t)b * NQS + q0 + qg * 8) * HH;
  float* outp = out + ((size_t)b * NQS + q0 + qg * 8) * NKS + k0 + kl;
#pragma unroll 2
  for (int j = 0; j < 8; ++j) {
    const float* ej = eqb + (size_t)j * HH;  // uniform -> s_load
    float acc = c0;
#pragma unroll
    for (int g = 0; g < 4; ++g) {
      float4 e0 = *(const float4*)(ej + g * 8);
      float4 e1 = *(const float4*)(ej + g * 8 + 4);
      const int i0 = 4 * g;
      // pair 0: h = 8g+0,1
      float da = fmaf(ek[8 * g + 0], e0.x, 1.f);
      float db = fmaf(ek[8 * g + 1], e0.y, 1.f);
      float dp0 = da * db;
      float np0 = fmaf(Aa[i0 + 0], e0.y, fmaf(Bb[i0 + 0], e0.x, C01[i0 + 0]));
      // pair 1: h = 8g+2,3
      da = fmaf(ek[8 * g + 2], e0.z, 1.f);
      db = fmaf(ek[8 * g + 3], e0.w, 1.f);
      float dp1 = da * db;
      float np1 = fmaf(Aa[i0 + 1], e0.w, fmaf(Bb[i0 + 1], e0.z, C01[i0 + 1]));
      // pair 2: h = 8g+4,5
      da = fmaf(ek[8 * g + 4], e1.x, 1.f);
      db = fmaf(ek[8 * g + 5], e1.y, 1.f);
      float dp2 = da * db;
      float np2 = fmaf(Aa[i0 + 2], e1.y, fmaf(Bb[i0 + 2], e1.x, C01[i0 + 2]));
      // pair 3: h = 8g+6,7
      da = fmaf(ek[8 * g + 6], e1.z, 1.f);
      db = fmaf(ek[8 * g + 7], e1.w, 1.f);
      float dp3 = da * db;
      float np3 = fmaf(Aa[i0 + 3], e1.w, fmaf(Bb[i0 + 3], e1.z, C01[i0 + 3]));
      // combine 4 rationals -> 1 rcp
      float d01 = dp0 * dp1, d23 = dp2 * dp3;
      float n01 = fmaf(np0, dp1, np1 * dp0);
      float n23 = fmaf(np2, dp3, np3 * dp2);
      float dd = d01 * d23;
      float nn = fmaf(n01, d23, n23 * d01);
      acc = fmaf(nn, frcp(dd), acc);
    }
    outp[(size_t)j * NKS] = acc;
  }
}

extern "C" void kernel_launch(void* const* d_in, const int* in_sizes, int n_in,
                              void* d_out, int out_size, void* d_ws, size_t ws_size,
                              hipStream_t stream) {
  const float* keys = (const float*)d_in[0];
  const float* queries = (const float*)d_in[1];
  const float* W1 = (const float*)d_in[2];
  const float* b1 = (const float*)d_in[3];
  const float* W2 = (const float*)d_in[4];
  const float* b2 = (const float*)d_in[5];
  float* out = (float*)d_out;
  float* ws = (float*)d_ws;  // E: [4096][32] fp32 = 512 KB

  hipLaunchKernelGGL(p1_proj_mfma, dim3(256), dim3(256), 0, stream,
                     keys, queries, W1, b1, ws);
  hipLaunchKernelGGL(p2_score, dim3(NKS / 64, NQS / 32, NB), dim3(256), 0, stream,
                     ws, W2, b2, out);
}